// Round 1
// baseline (5641.617 us; speedup 1.0000x reference)
//
#include <hip/hip_runtime.h>
#include <math.h>

typedef __bf16 bf16;
typedef __bf16 bf16x8 __attribute__((ext_vector_type(8)));
typedef float f32x4 __attribute__((ext_vector_type(4)));

#define DEV static __device__ __forceinline__

constexpr int NB    = 64;    // clips
constexpr int TCLIP = 784;   // tokens per clip
constexpr int TKF   = 196;   // keyframe tokens
constexpr int KKEEP = 147;   // kept keyframes
constexpr int NINC0 = 588;   // initial incremental tokens
constexpr int DIM   = 1024;
constexpr int MR    = NB * TKF;  // 12544 rows into the MLP
constexpr int NH    = 4096;

// ---- workspace layout (bytes, every chunk is a multiple of 256) ----
constexpr size_t OFF_W1T  = 0;
constexpr size_t OFF_W2T  = OFF_W1T  + (size_t)NH*DIM*2;       // w1^T bf16 (4096x1024)
constexpr size_t OFF_Z    = OFF_W2T  + (size_t)NH*NH*2;        // w2^T bf16 (4096x4096)
constexpr size_t OFF_H    = OFF_Z    + (size_t)MR*DIM*2;       // z bf16 (12544x1024)
constexpr size_t OFF_KFS  = OFF_H    + (size_t)MR*NH*2;        // h bf16 (12544x4096)
constexpr size_t OFF_KFAN = OFF_KFS  + (size_t)NB*KKEEP*DIM*4; // kf_sum f32
constexpr size_t OFF_KFC  = OFF_KFAN + (size_t)NB*KKEEP*DIM*4; // kf_avg normalized f32
constexpr size_t OFF_INV  = OFF_KFC  + (size_t)NB*KKEEP*4;     // kf_count f32
constexpr size_t OFF_S    = OFF_INV  + (size_t)NB*TCLIP*8;     // row inv-norms f64
constexpr size_t OFF_RED  = OFF_S    + (size_t)NB*DIM*8;       // kf_n column sums f64
constexpr size_t OFF_KSRC = OFF_RED  + (size_t)NB*TKF*4;       // redundancy f32
constexpr size_t OFF_IDXA = OFF_KSRC + (size_t)NB*KKEEP*4;
constexpr size_t OFF_IDXB = OFF_IDXA + (size_t)NB*NINC0*4;
constexpr size_t OFF_MAXS = OFF_IDXB + (size_t)NB*NINC0*4;
constexpr size_t OFF_BK   = OFF_MAXS + (size_t)NB*NINC0*4;
constexpr size_t OFF_MSRC = OFF_BK   + (size_t)NB*NINC0*4;
constexpr size_t OFF_MTGT = OFF_MSRC + (size_t)NB*TKF*4;

// ------------------------------------------------------------------
// transpose fp32 (R x C) -> bf16 (C x R)
__global__ void k_transpose_bf16(const float* __restrict__ in, bf16* __restrict__ out,
                                 int R, int C) {
  __shared__ float t[32][33];
  int c0 = blockIdx.x * 32, r0 = blockIdx.y * 32;
  int tx = threadIdx.x, ty = threadIdx.y;
#pragma unroll
  for (int i = 0; i < 4; i++) t[ty + 8*i][tx] = in[(size_t)(r0 + ty + 8*i) * C + c0 + tx];
  __syncthreads();
#pragma unroll
  for (int i = 0; i < 4; i++)
    out[(size_t)(c0 + ty + 8*i) * R + r0 + tx] = (bf16)t[tx][ty + 8*i];
}

// per-row 1/max(||row||,eps), fp64 accumulation, one block per row
__global__ void k_row_invnorm(const float* __restrict__ x, double* __restrict__ invn) {
  __shared__ double sm[256];
  int row = blockIdx.x, tid = threadIdx.x;
  const float* p = x + (size_t)row * DIM;
  double a = 0.0;
  for (int c = tid; c < DIM; c += 256) { double v = p[c]; a += v * v; }
  sm[tid] = a; __syncthreads();
#pragma unroll
  for (int s = 128; s >= 1; s >>= 1) { if (tid < s) sm[tid] += sm[tid + s]; __syncthreads(); }
  if (tid == 0) invn[row] = 1.0 / fmax(sqrt(sm[0]), 1e-12);
}

// S[b][c] = sum_i fp32(x_kf[b][i][c] * invn) ; fp64 accumulate, ascending i
__global__ void k_kf_colsum(const float* __restrict__ x, const double* __restrict__ invn,
                            double* __restrict__ S) {
  int b = blockIdx.x, tid = threadIdx.x;
  __shared__ double iv[TKF];
  for (int i = tid; i < TKF; i += 256) iv[i] = invn[b * TCLIP + i];
  __syncthreads();
  for (int c = tid; c < DIM; c += 256) {
    double s = 0.0;
    for (int i = 0; i < TKF; i++) {
      float kn = (float)((double)x[((size_t)b * TCLIP + i) * DIM + c] * iv[i]);
      s += (double)kn;
    }
    S[b * DIM + c] = s;
  }
}

// redundancy[b][i] = kf_n_i . S - 1
__global__ void k_redundancy(const float* __restrict__ x, const double* __restrict__ invn,
                             const double* __restrict__ S, float* __restrict__ red) {
  __shared__ double sm[256];
  int i = blockIdx.x, b = blockIdx.y, tid = threadIdx.x;
  const float* p = x + ((size_t)b * TCLIP + i) * DIM;
  double iv = invn[b * TCLIP + i];
  double a = 0.0;
  for (int c = tid; c < DIM; c += 256) {
    float kn = (float)((double)p[c] * iv);
    a += (double)kn * S[b * DIM + c];
  }
  sm[tid] = a; __syncthreads();
#pragma unroll
  for (int s = 128; s >= 1; s >>= 1) { if (tid < s) sm[tid] += sm[tid + s]; __syncthreads(); }
  if (tid == 0) red[b * TKF + i] = (float)(sm[0] - 1.0);
}

// keep 147 lowest-redundancy kf (stable ascending argsort), init count & incr index list
__global__ void k_select_kf(const float* __restrict__ red, int* __restrict__ kf_src,
                            float* __restrict__ kfcnt, int* __restrict__ idxA) {
  __shared__ float r[TKF];
  __shared__ int keep[TKF];
  int b = blockIdx.x, tid = threadIdx.x;
  if (tid < TKF) r[tid] = red[b * TKF + tid];
  __syncthreads();
  if (tid < TKF) {
    float ri = r[tid]; int rank = 0;
    for (int j = 0; j < TKF; j++) rank += (r[j] < ri) + ((j < tid) && (r[j] == ri));
    keep[tid] = rank < KKEEP;
  }
  __syncthreads();
  if (tid < TKF && keep[tid]) {
    int pos = 0;
    for (int j = 0; j < tid; j++) pos += keep[j];
    kf_src[b * KKEEP + pos] = tid;
  }
  if (tid < KKEEP) kfcnt[b * KKEEP + tid] = 1.0f;
  for (int u = tid; u < NINC0; u += 256) idxA[b * NINC0 + u] = u;
}

__global__ void k_gather_kf(const float* __restrict__ x, const int* __restrict__ kf_src,
                            float* __restrict__ kfsum) {
  int k = blockIdx.x, b = blockIdx.y, tid = threadIdx.x;
  int sr = kf_src[b * KKEEP + k];
  const float* s = x + ((size_t)b * TCLIP + sr) * DIM;
  float* d = kfsum + ((size_t)b * KKEEP + k) * DIM;
  for (int c = tid; c < DIM; c += 256) d[c] = s[c];
}

// kfan = l2norm(kf_sum / count), matching np's fp32 rounding points
__global__ void k_kfa(const float* __restrict__ kfsum, const float* __restrict__ kfcnt,
                      float* __restrict__ kfan) {
  __shared__ double sm[256];
  int k = blockIdx.x, b = blockIdx.y, tid = threadIdx.x;
  float cnt = kfcnt[b * KKEEP + k];
  const float* s = kfsum + ((size_t)b * KKEEP + k) * DIM;
  float* d = kfan + ((size_t)b * KKEEP + k) * DIM;
  float av[4]; double a = 0.0;
#pragma unroll
  for (int j = 0; j < 4; j++) { av[j] = s[tid + 256*j] / cnt; a += (double)av[j] * av[j]; }
  sm[tid] = a; __syncthreads();
#pragma unroll
  for (int sdt = 128; sdt >= 1; sdt >>= 1) { if (tid < sdt) sm[tid] += sm[tid + sdt]; __syncthreads(); }
  float nf = fmaxf((float)sqrt(sm[0]), 1e-12f);
#pragma unroll
  for (int j = 0; j < 4; j++) d[tid + 256*j] = av[j] / nf;
}

// sim_cross max/argmax over 147 kf for 8 incr tokens per block
template <int NI>
__global__ __launch_bounds__(256) void k_sim(const float* __restrict__ x,
                                             const double* __restrict__ invn,
                                             const float* __restrict__ kfan,
                                             const int* __restrict__ idx_cur,
                                             float* __restrict__ max_sim,
                                             int* __restrict__ best_kf) {
  __shared__ __align__(16) float T[8 * DIM];
  __shared__ float wmaxs[4][8];
  __shared__ int wargs[4][8];
  int b = blockIdx.y, p0 = blockIdx.x * 8, tid = threadIdx.x;
#pragma unroll
  for (int s = 0; s < 8; s++) {
    int p = p0 + s;
    if (p < NI) {
      int u = idx_cur[b * NINC0 + p];
      const float* r = x + ((size_t)b * TCLIP + TKF + u) * DIM;
      double iv = invn[b * TCLIP + TKF + u];
      for (int c = tid; c < DIM; c += 256) T[s * DIM + c] = (float)((double)r[c] * iv);
    } else {
      for (int c = tid; c < DIM; c += 256) T[s * DIM + c] = 0.f;
    }
  }
  __syncthreads();
  int w = tid >> 6, l = tid & 63;
  float bmax[8]; int barg[8];
#pragma unroll
  for (int s = 0; s < 8; s++) { bmax[s] = -3.0e38f; barg[s] = 1 << 30; }
  const f32x4* Tv = (const f32x4*)T;
  const f32x4 vzero = {0.f, 0.f, 0.f, 0.f};
  for (int t = 0; t < 10; t++) {          // ceil(147/16) rounds, wave w owns k = t*16 + w*4 + r
    int k0 = t * 16 + w * 4;
    f32x4 a[4][4];
#pragma unroll
    for (int r = 0; r < 4; r++) {
      int k = k0 + r;
      const f32x4* ap = (const f32x4*)(kfan + ((size_t)b * KKEEP + (k < KKEEP ? k : 0)) * DIM);
#pragma unroll
      for (int j = 0; j < 4; j++) a[r][j] = (k < KKEEP) ? ap[l + 64 * j] : vzero;
    }
    float accv[4][8];
#pragma unroll
    for (int r = 0; r < 4; r++)
#pragma unroll
      for (int s = 0; s < 8; s++) accv[r][s] = 0.f;
#pragma unroll
    for (int s = 0; s < 8; s++) {
#pragma unroll
      for (int j = 0; j < 4; j++) {
        f32x4 tv = Tv[s * 256 + l + 64 * j];
#pragma unroll
        for (int r = 0; r < 4; r++)
          accv[r][s] += a[r][j].x * tv.x + a[r][j].y * tv.y + a[r][j].z * tv.z + a[r][j].w * tv.w;
      }
    }
#pragma unroll
    for (int r = 0; r < 4; r++) {
      int k = k0 + r;
#pragma unroll
      for (int s = 0; s < 8; s++) {
        float v = accv[r][s];
#pragma unroll
        for (int off = 32; off > 0; off >>= 1) v += __shfl_xor(v, off, 64);
        if (k < KKEEP && v > bmax[s]) { bmax[s] = v; barg[s] = k; }  // ascending k: ties keep first
      }
    }
  }
  if (l == 0) {
#pragma unroll
    for (int s = 0; s < 8; s++) { wmaxs[w][s] = bmax[s]; wargs[w][s] = barg[s]; }
  }
  __syncthreads();
  if (tid < 8) {
    int s = tid; float bv = -3.0e38f; int bk = 1 << 30;
    for (int w2 = 0; w2 < 4; w2++) {
      float v = wmaxs[w2][s]; int k = wargs[w2][s];
      if (v > bv || (v == bv && k < bk)) { bv = v; bk = k; }
    }
    int p = p0 + s;
    if (p < NI) { max_sim[b * NINC0 + p] = bv; best_kf[b * NINC0 + p] = bk; }
  }
}

// stable descending rank of max_sim; emit merge list (rank order) + compacted keep list
template <int NI, int NM>
__global__ void k_rank_merge(const float* __restrict__ max_sim, const int* __restrict__ best_kf,
                             const int* __restrict__ idx_cur, int* __restrict__ idx_next,
                             int* __restrict__ msrc, int* __restrict__ mtgt) {
  __shared__ float s[NINC0];
  __shared__ short dr[NINC0];
  int b = blockIdx.x, tid = threadIdx.x;
  for (int i = tid; i < NI; i += 256) s[i] = max_sim[b * NINC0 + i];
  __syncthreads();
  for (int i = tid; i < NI; i += 256) {
    float si = s[i]; int cnt = 0;
    for (int j = 0; j < NI; j++) cnt += (s[j] > si) + ((j < i) && (s[j] == si));
    dr[i] = (short)cnt;
  }
  __syncthreads();
  for (int i = tid; i < NI; i += 256) {
    int r = dr[i];
    if (r < NM) {
      mtgt[b * TKF + r] = best_kf[b * NINC0 + i];
      msrc[b * TKF + r] = idx_cur[b * NINC0 + i];
    } else {
      int pos = 0;
      for (int j = 0; j < i; j++) pos += (dr[j] >= NM);
      idx_next[b * NINC0 + pos] = idx_cur[b * NINC0 + i];
    }
  }
}

// sequential (rank-order) scatter-add into kf_sum — matches np.add.at semantics
template <int NM>
__global__ void k_merge(const float* __restrict__ x, const int* __restrict__ msrc,
                        const int* __restrict__ mtgt, float* __restrict__ kfsum,
                        float* __restrict__ kfcnt) {
  int k = blockIdx.x, b = blockIdx.y, tid = threadIdx.x;
  float* drow = kfsum + ((size_t)b * KKEEP + k) * DIM;
  float acc[4];
#pragma unroll
  for (int j = 0; j < 4; j++) acc[j] = drow[tid + 256*j];
  int adds = 0;
  for (int m = 0; m < NM; m++) {
    int tgt = mtgt[b * TKF + m];
    if (tgt == k) {
      int u = msrc[b * TKF + m];
      const float* r = x + ((size_t)b * TCLIP + TKF + u) * DIM;
#pragma unroll
      for (int j = 0; j < 4; j++) acc[j] += r[tid + 256*j];
      adds++;
    }
  }
#pragma unroll
  for (int j = 0; j < 4; j++) drow[tid + 256*j] = acc[j];
  if (tid == 0 && adds) kfcnt[b * KKEEP + k] += (float)adds;
}

// z = concat(kf_sum/count, kept incr) -> bf16
__global__ void k_assemble_z(const float* __restrict__ x, const float* __restrict__ kfsum,
                             const float* __restrict__ kfcnt, const int* __restrict__ idx_fin,
                             bf16* __restrict__ z) {
  int r = blockIdx.x, b = blockIdx.y, tid = threadIdx.x;
  bf16* zr = z + ((size_t)b * TKF + r) * DIM;
  if (r < KKEEP) {
    float cnt = kfcnt[b * KKEEP + r];
    const float* s = kfsum + ((size_t)b * KKEEP + r) * DIM;
    for (int c = tid; c < DIM; c += 256) zr[c] = (bf16)(s[c] / cnt);
  } else {
    int u = idx_fin[b * NINC0 + (r - KKEEP)];
    const float* s = x + ((size_t)b * TCLIP + TKF + u) * DIM;
    for (int c = tid; c < DIM; c += 256) zr[c] = (bf16)s[c];
  }
}

// ---- m97-style bf16 GEMM: C = A(MxK) * Bt(NxK)^T, 128x128 tile, BK=32 ----
DEV void gl2lds16(const bf16* g, bf16* l) {
  __builtin_amdgcn_global_load_lds((const __attribute__((address_space(1))) void*)g,
                                   (__attribute__((address_space(3))) void*)l, 16, 0, 0);
}

template <int EPI>  // 0: +bias, exact gelu, store bf16 ; 1: +bias, store fp32
__global__ __launch_bounds__(256) void k_gemm_bt(const bf16* __restrict__ A,
                                                 const bf16* __restrict__ Bt,
                                                 const float* __restrict__ bias,
                                                 float* __restrict__ outF,
                                                 bf16* __restrict__ outB, int K) {
  __shared__ __align__(16) bf16 As[128 * 32];
  __shared__ __align__(16) bf16 Bs[128 * 32];
  int tid = threadIdx.x, w = tid >> 6, l = tid & 63;
  int m0 = blockIdx.x * 128, n0 = blockIdx.y * 128;
  int wr = w >> 1, wc = w & 1;
  f32x4 acc[4][4];
#pragma unroll
  for (int i = 0; i < 4; i++)
#pragma unroll
    for (int j = 0; j < 4; j++) acc[i][j] = f32x4{0.f, 0.f, 0.f, 0.f};

  int srow = w * 32 + (l >> 2);
  int scol = (l & 3) * 8;
  const bf16* gA = A + (size_t)(m0 + srow) * K + scol;
  const bf16* gB = Bt + (size_t)(n0 + srow) * K + scol;
  const size_t str16 = (size_t)16 * K;
  bf16* lA0 = As + (w * 32) * 32;
  bf16* lA1 = As + (w * 32 + 16) * 32;
  bf16* lB0 = Bs + (w * 32) * 32;
  bf16* lB1 = Bs + (w * 32 + 16) * 32;

  int fro = (l & 15), ko = (l >> 4) * 8;
  for (int kk = 0; kk < K; kk += 32) {
    __syncthreads();
    gl2lds16(gA + kk, lA0);
    gl2lds16(gA + kk + str16, lA1);
    gl2lds16(gB + kk, lB0);
    gl2lds16(gB + kk + str16, lB1);
    __syncthreads();
    bf16x8 af[4], bfr[4];
#pragma unroll
    for (int mi = 0; mi < 4; mi++)
      af[mi] = *(const bf16x8*)(As + (wr * 64 + mi * 16 + fro) * 32 + ko);
#pragma unroll
    for (int ni = 0; ni < 4; ni++)
      bfr[ni] = *(const bf16x8*)(Bs + (wc * 64 + ni * 16 + fro) * 32 + ko);
#pragma unroll
    for (int mi = 0; mi < 4; mi++)
#pragma unroll
      for (int ni = 0; ni < 4; ni++)
        acc[mi][ni] = __builtin_amdgcn_mfma_f32_16x16x32_bf16(af[mi], bfr[ni], acc[mi][ni], 0, 0, 0);
  }
  int col0 = n0 + wc * 64 + (l & 15);
  int row0 = m0 + wr * 64 + ((l >> 4) << 2);
#pragma unroll
  for (int ni = 0; ni < 4; ni++) {
    int col = col0 + ni * 16;
    float bv = bias[col];
#pragma unroll
    for (int mi = 0; mi < 4; mi++) {
#pragma unroll
      for (int r = 0; r < 4; r++) {
        int row = row0 + mi * 16 + r;
        float v = acc[mi][ni][r] + bv;
        if (EPI == 0) {
          float g = 0.5f * v * (1.0f + erff(v * 0.70710678118654752f));
          outB[(size_t)row * NH + col] = (bf16)g;
        } else {
          outF[(size_t)row * NH + col] = v;
        }
      }
    }
  }
}

// ------------------------------------------------------------------
template <int NI, int NM>
static void run_iter(const float* x, const double* INV, float* KFS, float* KFC, float* KFAN,
                     const int* cur, int* next, float* MAXS, int* BK, int* MSRC, int* MTGT,
                     hipStream_t stream) {
  k_kfa<<<dim3(KKEEP, NB), 256, 0, stream>>>(KFS, KFC, KFAN);
  k_sim<NI><<<dim3((NI + 7) / 8, NB), 256, 0, stream>>>(x, INV, KFAN, cur, MAXS, BK);
  k_rank_merge<NI, NM><<<NB, 256, 0, stream>>>(MAXS, BK, cur, next, MSRC, MTGT);
  k_merge<NM><<<dim3(KKEEP, NB), 256, 0, stream>>>(x, MSRC, MTGT, KFS, KFC);
}

extern "C" void kernel_launch(void* const* d_in, const int* in_sizes, int n_in,
                              void* d_out, int out_size, void* d_ws, size_t ws_size,
                              hipStream_t stream) {
  const float* x  = (const float*)d_in[0];
  const float* w1 = (const float*)d_in[1];
  const float* b1 = (const float*)d_in[2];
  const float* w2 = (const float*)d_in[3];
  const float* b2 = (const float*)d_in[4];
  float* out = (float*)d_out;
  char* ws = (char*)d_ws;

  bf16*   W1T  = (bf16*)(ws + OFF_W1T);
  bf16*   W2T  = (bf16*)(ws + OFF_W2T);
  bf16*   Z    = (bf16*)(ws + OFF_Z);
  bf16*   H    = (bf16*)(ws + OFF_H);
  float*  KFS  = (float*)(ws + OFF_KFS);
  float*  KFAN = (float*)(ws + OFF_KFAN);
  float*  KFC  = (float*)(ws + OFF_KFC);
  double* INV  = (double*)(ws + OFF_INV);
  double* S    = (double*)(ws + OFF_S);
  float*  RED  = (float*)(ws + OFF_RED);
  int*    KSRC = (int*)(ws + OFF_KSRC);
  int*    IDXA = (int*)(ws + OFF_IDXA);
  int*    IDXB = (int*)(ws + OFF_IDXB);
  float*  MAXS = (float*)(ws + OFF_MAXS);
  int*    BK   = (int*)(ws + OFF_BK);
  int*    MSRC = (int*)(ws + OFF_MSRC);
  int*    MTGT = (int*)(ws + OFF_MTGT);

  // weight transpose + bf16 convert
  k_transpose_bf16<<<dim3(NH / 32, DIM / 32), dim3(32, 8), 0, stream>>>(w1, W1T, DIM, NH);
  k_transpose_bf16<<<dim3(NH / 32, NH / 32), dim3(32, 8), 0, stream>>>(w2, W2T, NH, NH);

  // compression setup
  k_row_invnorm<<<NB * TCLIP, 256, 0, stream>>>(x, INV);
  k_kf_colsum<<<NB, 256, 0, stream>>>(x, INV, S);
  k_redundancy<<<dim3(TKF, NB), 256, 0, stream>>>(x, INV, S, RED);
  k_select_kf<<<NB, 256, 0, stream>>>(RED, KSRC, KFC, IDXA);
  k_gather_kf<<<dim3(KKEEP, NB), 256, 0, stream>>>(x, KSRC, KFS);

  // 7 fixed merge iterations: (n_incr, n_to_merge)
  run_iter<588, 196>(x, INV, KFS, KFC, KFAN, IDXA, IDXB, MAXS, BK, MSRC, MTGT, stream);
  run_iter<392, 130>(x, INV, KFS, KFC, KFAN, IDXB, IDXA, MAXS, BK, MSRC, MTGT, stream);
  run_iter<262,  87>(x, INV, KFS, KFC, KFAN, IDXA, IDXB, MAXS, BK, MSRC, MTGT, stream);
  run_iter<175,  58>(x, INV, KFS, KFC, KFAN, IDXB, IDXA, MAXS, BK, MSRC, MTGT, stream);
  run_iter<117,  39>(x, INV, KFS, KFC, KFAN, IDXA, IDXB, MAXS, BK, MSRC, MTGT, stream);
  run_iter< 78,  26>(x, INV, KFS, KFC, KFAN, IDXB, IDXA, MAXS, BK, MSRC, MTGT, stream);
  run_iter< 52,   3>(x, INV, KFS, KFC, KFAN, IDXA, IDXB, MAXS, BK, MSRC, MTGT, stream);

  k_assemble_z<<<dim3(TKF, NB), 256, 0, stream>>>(x, KFS, KFC, IDXB, Z);

  // MLP: h = gelu(z@w1 + b1) ; out = h@w2 + b2
  k_gemm_bt<0><<<dim3(MR / 128, NH / 128), 256, 0, stream>>>(Z, W1T, b1, nullptr, H, DIM);
  k_gemm_bt<1><<<dim3(MR / 128, NH / 128), 256, 0, stream>>>(H, W2T, b2, out, nullptr, NH);
}

// Round 2
// 2590.531 us; speedup vs baseline: 2.1778x; 2.1778x over previous
//
#include <hip/hip_runtime.h>
#include <math.h>

typedef __bf16 bf16;
typedef __bf16 bf16x8 __attribute__((ext_vector_type(8)));
typedef float f32x4 __attribute__((ext_vector_type(4)));

#define DEV static __device__ __forceinline__

constexpr int NB    = 64;    // clips
constexpr int TCLIP = 784;   // tokens per clip
constexpr int TKF   = 196;   // keyframe tokens
constexpr int KKEEP = 147;   // kept keyframes
constexpr int NINC0 = 588;   // initial incremental tokens
constexpr int DIM   = 1024;
constexpr int MR    = NB * TKF;  // 12544 rows into the MLP
constexpr int NH    = 4096;

// ---- workspace layout (bytes) ----
constexpr size_t OFF_W1T  = 0;
constexpr size_t OFF_W2T  = OFF_W1T  + (size_t)NH*DIM*2;       // w1^T bf16 (4096x1024)
constexpr size_t OFF_Z    = OFF_W2T  + (size_t)NH*NH*2;        // w2^T bf16 (4096x4096)
constexpr size_t OFF_H    = OFF_Z    + (size_t)MR*DIM*2;       // z bf16 (12544x1024)
constexpr size_t OFF_KFS  = OFF_H    + (size_t)MR*NH*2;        // h bf16 (12544x4096)
constexpr size_t OFF_KFC  = OFF_KFS  + (size_t)NB*KKEEP*DIM*4; // kf_sum f32
constexpr size_t OFF_INV  = OFF_KFC  + (size_t)NB*KKEEP*4;     // kf_count f32
constexpr size_t OFF_S    = OFF_INV  + (size_t)NB*TCLIP*8;     // row inv-norms f64
constexpr size_t OFF_RED  = OFF_S    + (size_t)NB*DIM*8;       // kf_n column sums f64
constexpr size_t OFF_KSRC = OFF_RED  + (size_t)NB*TKF*4;       // redundancy f32
constexpr size_t OFF_IDXA = OFF_KSRC + (size_t)NB*KKEEP*4;
constexpr size_t OFF_IDXB = OFF_IDXA + (size_t)NB*NINC0*4;
constexpr size_t OFF_MAXS = OFF_IDXB + (size_t)NB*NINC0*4;
constexpr size_t OFF_BK   = OFF_MAXS + (size_t)NB*NINC0*4;
constexpr size_t OFF_MSRC = OFF_BK   + (size_t)NB*NINC0*4;
constexpr size_t OFF_MTGT = OFF_MSRC + (size_t)NB*TKF*4;
// kfan 3-way bf16 splits live in the H region (GEMM1 output, written only
// after the merge iterations finish): 3 * 64*147*1024*2B = 57.9 MB <= 102.8 MB
constexpr size_t KFA_ELT  = (size_t)NB * KKEEP * DIM;

// ------------------------------------------------------------------
// transpose fp32 (R x C) -> bf16 (C x R)
__global__ void k_transpose_bf16(const float* __restrict__ in, bf16* __restrict__ out,
                                 int R, int C) {
  __shared__ float t[32][33];
  int c0 = blockIdx.x * 32, r0 = blockIdx.y * 32;
  int tx = threadIdx.x, ty = threadIdx.y;
#pragma unroll
  for (int i = 0; i < 4; i++) t[ty + 8*i][tx] = in[(size_t)(r0 + ty + 8*i) * C + c0 + tx];
  __syncthreads();
#pragma unroll
  for (int i = 0; i < 4; i++)
    out[(size_t)(c0 + ty + 8*i) * R + r0 + tx] = (bf16)t[tx][ty + 8*i];
}

// per-row 1/max(||row||,eps), fp64 accumulation, one block per row
__global__ void k_row_invnorm(const float* __restrict__ x, double* __restrict__ invn) {
  __shared__ double sm[256];
  int row = blockIdx.x, tid = threadIdx.x;
  const float* p = x + (size_t)row * DIM;
  double a = 0.0;
  for (int c = tid; c < DIM; c += 256) { double v = p[c]; a += v * v; }
  sm[tid] = a; __syncthreads();
#pragma unroll
  for (int s = 128; s >= 1; s >>= 1) { if (tid < s) sm[tid] += sm[tid + s]; __syncthreads(); }
  if (tid == 0) invn[row] = 1.0 / fmax(sqrt(sm[0]), 1e-12);
}

// S[b][c] = sum_i fp32(x_kf[b][i][c] * invn) ; fp64 accumulate, ascending i
__global__ void k_kf_colsum(const float* __restrict__ x, const double* __restrict__ invn,
                            double* __restrict__ S) {
  int b = blockIdx.x, tid = threadIdx.x;
  __shared__ double iv[TKF];
  for (int i = tid; i < TKF; i += 256) iv[i] = invn[b * TCLIP + i];
  __syncthreads();
  for (int c = tid; c < DIM; c += 256) {
    double s = 0.0;
    for (int i = 0; i < TKF; i++) {
      float kn = (float)((double)x[((size_t)b * TCLIP + i) * DIM + c] * iv[i]);
      s += (double)kn;
    }
    S[b * DIM + c] = s;
  }
}

// redundancy[b][i] = kf_n_i . S - 1
__global__ void k_redundancy(const float* __restrict__ x, const double* __restrict__ invn,
                             const double* __restrict__ S, float* __restrict__ red) {
  __shared__ double sm[256];
  int i = blockIdx.x, b = blockIdx.y, tid = threadIdx.x;
  const float* p = x + ((size_t)b * TCLIP + i) * DIM;
  double iv = invn[b * TCLIP + i];
  double a = 0.0;
  for (int c = tid; c < DIM; c += 256) {
    float kn = (float)((double)p[c] * iv);
    a += (double)kn * S[b * DIM + c];
  }
  sm[tid] = a; __syncthreads();
#pragma unroll
  for (int s = 128; s >= 1; s >>= 1) { if (tid < s) sm[tid] += sm[tid + s]; __syncthreads(); }
  if (tid == 0) red[b * TKF + i] = (float)(sm[0] - 1.0);
}

// keep 147 lowest-redundancy kf (stable ascending argsort), init count & incr index list
__global__ void k_select_kf(const float* __restrict__ red, int* __restrict__ kf_src,
                            float* __restrict__ kfcnt, int* __restrict__ idxA) {
  __shared__ float r[TKF];
  __shared__ int keep[TKF];
  int b = blockIdx.x, tid = threadIdx.x;
  if (tid < TKF) r[tid] = red[b * TKF + tid];
  __syncthreads();
  if (tid < TKF) {
    float ri = r[tid]; int rank = 0;
    for (int j = 0; j < TKF; j++) rank += (r[j] < ri) + ((j < tid) && (r[j] == ri));
    keep[tid] = rank < KKEEP;
  }
  __syncthreads();
  if (tid < TKF && keep[tid]) {
    int pos = 0;
    for (int j = 0; j < tid; j++) pos += keep[j];
    kf_src[b * KKEEP + pos] = tid;
  }
  if (tid < KKEEP) kfcnt[b * KKEEP + tid] = 1.0f;
  for (int u = tid; u < NINC0; u += 256) idxA[b * NINC0 + u] = u;
}

__global__ void k_gather_kf(const float* __restrict__ x, const int* __restrict__ kf_src,
                            float* __restrict__ kfsum) {
  int k = blockIdx.x, b = blockIdx.y, tid = threadIdx.x;
  int sr = kf_src[b * KKEEP + k];
  const float* s = x + ((size_t)b * TCLIP + sr) * DIM;
  float* d = kfsum + ((size_t)b * KKEEP + k) * DIM;
  for (int c = tid; c < DIM; c += 256) d[c] = s[c];
}

// kfan = l2norm(kf_sum / count) in fp32, emitted as 3-way bf16 split (hi+mid+lo)
__global__ void k_kfa(const float* __restrict__ kfsum, const float* __restrict__ kfcnt,
                      bf16* __restrict__ khi, bf16* __restrict__ kmid,
                      bf16* __restrict__ klo) {
  __shared__ double sm[256];
  int k = blockIdx.x, b = blockIdx.y, tid = threadIdx.x;
  float cnt = kfcnt[b * KKEEP + k];
  size_t base = ((size_t)b * KKEEP + k) * DIM;
  const float* s = kfsum + base;
  float av[4]; double a = 0.0;
#pragma unroll
  for (int j = 0; j < 4; j++) { av[j] = s[tid + 256*j] / cnt; a += (double)av[j] * av[j]; }
  sm[tid] = a; __syncthreads();
#pragma unroll
  for (int sdt = 128; sdt >= 1; sdt >>= 1) { if (tid < sdt) sm[tid] += sm[tid + sdt]; __syncthreads(); }
  float nf = fmaxf((float)sqrt(sm[0]), 1e-12f);
#pragma unroll
  for (int j = 0; j < 4; j++) {
    float v = av[j] / nf;
    bf16 h = (bf16)v;
    float r1 = v - (float)h;
    bf16 m = (bf16)r1;
    float r2 = r1 - (float)m;
    khi[base + tid + 256*j]  = h;
    kmid[base + tid + 256*j] = m;
    klo[base + tid + 256*j]  = (bf16)r2;
  }
}

// ---- MFMA emulated-fp32 sim + fused column max/argmax ----
// block = (64-col incr stripe, clip b); wave w owns col tile w (16 cols) x all
// 160 padded kf rows. fp32 ~= hi+mid+lo bf16; keep 6 product terms (err ~2^-26).
template <int NI>
__global__ __launch_bounds__(256) void k_sim_mfma(const float* __restrict__ x,
                                                  const double* __restrict__ invn,
                                                  const bf16* __restrict__ khi,
                                                  const bf16* __restrict__ kmid,
                                                  const bf16* __restrict__ klo,
                                                  const int* __restrict__ idx_cur,
                                                  float* __restrict__ max_sim,
                                                  int* __restrict__ best_kf) {
  __shared__ __align__(16) bf16 Ah[160 * 32];
  __shared__ __align__(16) bf16 Am[160 * 32];
  __shared__ __align__(16) bf16 Al[160 * 32];
  __shared__ __align__(16) bf16 Bh[64 * 32];
  __shared__ __align__(16) bf16 Bm[64 * 32];
  __shared__ __align__(16) bf16 Bl[64 * 32];
  __shared__ int toks[64];
  __shared__ double ivv[64];

  int b = blockIdx.y, p0 = blockIdx.x * 64, tid = threadIdx.x;
  int w = tid >> 6, l = tid & 63;

  if (tid < 64) {
    int p = p0 + tid;
    bool ok = p < NI;
    toks[tid] = ok ? idx_cur[b * NINC0 + p] : 0;
    ivv[tid] = ok ? invn[b * TCLIP + TKF + toks[tid]] : 0.0;
  }

  f32x4 acc[10];
#pragma unroll
  for (int t = 0; t < 10; t++) acc[t] = f32x4{0.f, 0.f, 0.f, 0.f};

  int brow = tid >> 2;              // B staging: token row 0..63
  int bko  = (tid & 3) * 8;         // 8 k-elements
  size_t kbase = (size_t)b * KKEEP * DIM;

  for (int kk = 0; kk < DIM; kk += 32) {
    __syncthreads();
    // stage kfan splits: 160 rows x 32 k (rows >=147 zero), 16B chunks
#pragma unroll
    for (int j = 0; j < 3; j++) {
      int c = tid + 256 * j;
      if (c < 640) {
        int row = c >> 2, off8 = (c & 3) * 8;
        uint4 vh = {0,0,0,0}, vm = {0,0,0,0}, vl = {0,0,0,0};
        if (row < KKEEP) {
          size_t g = kbase + (size_t)row * DIM + kk + off8;
          vh = *(const uint4*)(khi + g);
          vm = *(const uint4*)(kmid + g);
          vl = *(const uint4*)(klo + g);
        }
        *(uint4*)(Ah + row * 32 + off8) = vh;
        *(uint4*)(Am + row * 32 + off8) = vm;
        *(uint4*)(Al + row * 32 + off8) = vl;
      }
    }
    // stage incr tile: 64 rows x 32 k fp32 -> 3-way split
    {
      const float* src = x + ((size_t)b * TCLIP + TKF + toks[brow]) * DIM + kk + bko;
      double iv = ivv[brow];
      float4 f0 = *(const float4*)src;
      float4 f1 = *(const float4*)(src + 4);
      float vv[8] = {f0.x, f0.y, f0.z, f0.w, f1.x, f1.y, f1.z, f1.w};
#pragma unroll
      for (int e = 0; e < 8; e++) {
        float v = (float)((double)vv[e] * iv);
        bf16 h = (bf16)v;
        float r1 = v - (float)h;
        bf16 m = (bf16)r1;
        float r2 = r1 - (float)m;
        int o = brow * 32 + bko + e;
        Bh[o] = h; Bm[o] = m; Bl[o] = (bf16)r2;
      }
    }
    __syncthreads();

    int fo = ((w * 16 + (l & 15)) << 5) + ((l >> 4) << 3);
    bf16x8 fbh = *(const bf16x8*)(Bh + fo);
    bf16x8 fbm = *(const bf16x8*)(Bm + fo);
    bf16x8 fbl = *(const bf16x8*)(Bl + fo);
#pragma unroll
    for (int t = 0; t < 10; t++) {
      int ao = ((t * 16 + (l & 15)) << 5) + ((l >> 4) << 3);
      bf16x8 fah = *(const bf16x8*)(Ah + ao);
      bf16x8 fam = *(const bf16x8*)(Am + ao);
      bf16x8 fal = *(const bf16x8*)(Al + ao);
      acc[t] = __builtin_amdgcn_mfma_f32_16x16x32_bf16(fah, fbh, acc[t], 0, 0, 0);
      acc[t] = __builtin_amdgcn_mfma_f32_16x16x32_bf16(fah, fbm, acc[t], 0, 0, 0);
      acc[t] = __builtin_amdgcn_mfma_f32_16x16x32_bf16(fam, fbh, acc[t], 0, 0, 0);
      acc[t] = __builtin_amdgcn_mfma_f32_16x16x32_bf16(fam, fbm, acc[t], 0, 0, 0);
      acc[t] = __builtin_amdgcn_mfma_f32_16x16x32_bf16(fah, fbl, acc[t], 0, 0, 0);
      acc[t] = __builtin_amdgcn_mfma_f32_16x16x32_bf16(fal, fbh, acc[t], 0, 0, 0);
    }
  }

  // per-lane max over rows (ascending => ties keep lowest kf)
  float vmax = -3.0e38f; int varg = 1 << 30;
  int g4 = (l >> 4) << 2;
#pragma unroll
  for (int t = 0; t < 10; t++) {
#pragma unroll
    for (int r = 0; r < 4; r++) {
      int row = t * 16 + g4 + r;
      float v = acc[t][r];
      if (row < KKEEP && v > vmax) { vmax = v; varg = row; }
    }
  }
  // combine across the 4 row-groups
#pragma unroll
  for (int off = 16; off <= 32; off <<= 1) {
    float ov = __shfl_xor(vmax, off, 64);
    int   oa = __shfl_xor(varg, off, 64);
    if (ov > vmax || (ov == vmax && oa < varg)) { vmax = ov; varg = oa; }
  }
  if (l < 16) {
    int p = p0 + w * 16 + l;
    if (p < NI) { max_sim[b * NINC0 + p] = vmax; best_kf[b * NINC0 + p] = varg; }
  }
}

// stable descending rank of max_sim; emit merge list (rank order) + compacted keep list
template <int NI, int NM>
__global__ void k_rank_merge(const float* __restrict__ max_sim, const int* __restrict__ best_kf,
                             const int* __restrict__ idx_cur, int* __restrict__ idx_next,
                             int* __restrict__ msrc, int* __restrict__ mtgt) {
  __shared__ float s[NINC0];
  __shared__ short dr[NINC0];
  int b = blockIdx.x, tid = threadIdx.x;
  for (int i = tid; i < NI; i += 256) s[i] = max_sim[b * NINC0 + i];
  __syncthreads();
  for (int i = tid; i < NI; i += 256) {
    float si = s[i]; int cnt = 0;
    for (int j = 0; j < NI; j++) cnt += (s[j] > si) + ((j < i) && (s[j] == si));
    dr[i] = (short)cnt;
  }
  __syncthreads();
  for (int i = tid; i < NI; i += 256) {
    int r = dr[i];
    if (r < NM) {
      mtgt[b * TKF + r] = best_kf[b * NINC0 + i];
      msrc[b * TKF + r] = idx_cur[b * NINC0 + i];
    } else {
      int pos = 0;
      for (int j = 0; j < i; j++) pos += (dr[j] >= NM);
      idx_next[b * NINC0 + pos] = idx_cur[b * NINC0 + i];
    }
  }
}

// sequential (rank-order) scatter-add into kf_sum — matches np.add.at semantics
template <int NM>
__global__ void k_merge(const float* __restrict__ x, const int* __restrict__ msrc,
                        const int* __restrict__ mtgt, float* __restrict__ kfsum,
                        float* __restrict__ kfcnt) {
  int k = blockIdx.x, b = blockIdx.y, tid = threadIdx.x;
  float* drow = kfsum + ((size_t)b * KKEEP + k) * DIM;
  float acc[4];
#pragma unroll
  for (int j = 0; j < 4; j++) acc[j] = drow[tid + 256*j];
  int adds = 0;
  for (int m = 0; m < NM; m++) {
    int tgt = mtgt[b * TKF + m];
    if (tgt == k) {
      int u = msrc[b * TKF + m];
      const float* r = x + ((size_t)b * TCLIP + TKF + u) * DIM;
#pragma unroll
      for (int j = 0; j < 4; j++) acc[j] += r[tid + 256*j];
      adds++;
    }
  }
#pragma unroll
  for (int j = 0; j < 4; j++) drow[tid + 256*j] = acc[j];
  if (tid == 0 && adds) kfcnt[b * KKEEP + k] += (float)adds;
}

// z = concat(kf_sum/count, kept incr) -> bf16
__global__ void k_assemble_z(const float* __restrict__ x, const float* __restrict__ kfsum,
                             const float* __restrict__ kfcnt, const int* __restrict__ idx_fin,
                             bf16* __restrict__ z) {
  int r = blockIdx.x, b = blockIdx.y, tid = threadIdx.x;
  bf16* zr = z + ((size_t)b * TKF + r) * DIM;
  if (r < KKEEP) {
    float cnt = kfcnt[b * KKEEP + r];
    const float* s = kfsum + ((size_t)b * KKEEP + r) * DIM;
    for (int c = tid; c < DIM; c += 256) zr[c] = (bf16)(s[c] / cnt);
  } else {
    int u = idx_fin[b * NINC0 + (r - KKEEP)];
    const float* s = x + ((size_t)b * TCLIP + TKF + u) * DIM;
    for (int c = tid; c < DIM; c += 256) zr[c] = (bf16)s[c];
  }
}

// ---- m97-style bf16 GEMM: C = A(MxK) * Bt(NxK)^T, 128x128 tile, BK=32 ----
DEV void gl2lds16(const bf16* g, bf16* l) {
  __builtin_amdgcn_global_load_lds((const __attribute__((address_space(1))) void*)g,
                                   (__attribute__((address_space(3))) void*)l, 16, 0, 0);
}

template <int EPI>  // 0: +bias, exact gelu, store bf16 ; 1: +bias, store fp32
__global__ __launch_bounds__(256) void k_gemm_bt(const bf16* __restrict__ A,
                                                 const bf16* __restrict__ Bt,
                                                 const float* __restrict__ bias,
                                                 float* __restrict__ outF,
                                                 bf16* __restrict__ outB, int K) {
  __shared__ __align__(16) bf16 As[128 * 32];
  __shared__ __align__(16) bf16 Bs[128 * 32];
  int tid = threadIdx.x, w = tid >> 6, l = tid & 63;
  int m0 = blockIdx.x * 128, n0 = blockIdx.y * 128;
  int wr = w >> 1, wc = w & 1;
  f32x4 acc[4][4];
#pragma unroll
  for (int i = 0; i < 4; i++)
#pragma unroll
    for (int j = 0; j < 4; j++) acc[i][j] = f32x4{0.f, 0.f, 0.f, 0.f};

  int srow = w * 32 + (l >> 2);
  int scol = (l & 3) * 8;
  const bf16* gA = A + (size_t)(m0 + srow) * K + scol;
  const bf16* gB = Bt + (size_t)(n0 + srow) * K + scol;
  const size_t str16 = (size_t)16 * K;
  bf16* lA0 = As + (w * 32) * 32;
  bf16* lA1 = As + (w * 32 + 16) * 32;
  bf16* lB0 = Bs + (w * 32) * 32;
  bf16* lB1 = Bs + (w * 32 + 16) * 32;

  int fro = (l & 15), ko = (l >> 4) * 8;
  for (int kk = 0; kk < K; kk += 32) {
    __syncthreads();
    gl2lds16(gA + kk, lA0);
    gl2lds16(gA + kk + str16, lA1);
    gl2lds16(gB + kk, lB0);
    gl2lds16(gB + kk + str16, lB1);
    __syncthreads();
    bf16x8 af[4], bfr[4];
#pragma unroll
    for (int mi = 0; mi < 4; mi++)
      af[mi] = *(const bf16x8*)(As + (wr * 64 + mi * 16 + fro) * 32 + ko);
#pragma unroll
    for (int ni = 0; ni < 4; ni++)
      bfr[ni] = *(const bf16x8*)(Bs + (wc * 64 + ni * 16 + fro) * 32 + ko);
#pragma unroll
    for (int mi = 0; mi < 4; mi++)
#pragma unroll
      for (int ni = 0; ni < 4; ni++)
        acc[mi][ni] = __builtin_amdgcn_mfma_f32_16x16x32_bf16(af[mi], bfr[ni], acc[mi][ni], 0, 0, 0);
  }
  int col0 = n0 + wc * 64 + (l & 15);
  int row0 = m0 + wr * 64 + ((l >> 4) << 2);
#pragma unroll
  for (int ni = 0; ni < 4; ni++) {
    int col = col0 + ni * 16;
    float bv = bias[col];
#pragma unroll
    for (int mi = 0; mi < 4; mi++) {
#pragma unroll
      for (int r = 0; r < 4; r++) {
        int row = row0 + mi * 16 + r;
        float v = acc[mi][ni][r] + bv;
        if (EPI == 0) {
          float g = 0.5f * v * (1.0f + erff(v * 0.70710678118654752f));
          outB[(size_t)row * NH + col] = (bf16)g;
        } else {
          outF[(size_t)row * NH + col] = v;
        }
      }
    }
  }
}

// ------------------------------------------------------------------
template <int NI, int NM>
static void run_iter(const float* x, const double* INV, float* KFS, float* KFC,
                     bf16* KH, bf16* KM, bf16* KL,
                     const int* cur, int* next, float* MAXS, int* BK, int* MSRC, int* MTGT,
                     hipStream_t stream) {
  k_kfa<<<dim3(KKEEP, NB), 256, 0, stream>>>(KFS, KFC, KH, KM, KL);
  k_sim_mfma<NI><<<dim3((NI + 63) / 64, NB), 256, 0, stream>>>(x, INV, KH, KM, KL, cur, MAXS, BK);
  k_rank_merge<NI, NM><<<NB, 256, 0, stream>>>(MAXS, BK, cur, next, MSRC, MTGT);
  k_merge<NM><<<dim3(KKEEP, NB), 256, 0, stream>>>(x, MSRC, MTGT, KFS, KFC);
}

extern "C" void kernel_launch(void* const* d_in, const int* in_sizes, int n_in,
                              void* d_out, int out_size, void* d_ws, size_t ws_size,
                              hipStream_t stream) {
  const float* x  = (const float*)d_in[0];
  const float* w1 = (const float*)d_in[1];
  const float* b1 = (const float*)d_in[2];
  const float* w2 = (const float*)d_in[3];
  const float* b2 = (const float*)d_in[4];
  float* out = (float*)d_out;
  char* ws = (char*)d_ws;

  bf16*   W1T  = (bf16*)(ws + OFF_W1T);
  bf16*   W2T  = (bf16*)(ws + OFF_W2T);
  bf16*   Z    = (bf16*)(ws + OFF_Z);
  bf16*   H    = (bf16*)(ws + OFF_H);
  float*  KFS  = (float*)(ws + OFF_KFS);
  float*  KFC  = (float*)(ws + OFF_KFC);
  double* INV  = (double*)(ws + OFF_INV);
  double* S    = (double*)(ws + OFF_S);
  float*  RED  = (float*)(ws + OFF_RED);
  int*    KSRC = (int*)(ws + OFF_KSRC);
  int*    IDXA = (int*)(ws + OFF_IDXA);
  int*    IDXB = (int*)(ws + OFF_IDXB);
  float*  MAXS = (float*)(ws + OFF_MAXS);
  int*    BK   = (int*)(ws + OFF_BK);
  int*    MSRC = (int*)(ws + OFF_MSRC);
  int*    MTGT = (int*)(ws + OFF_MTGT);
  // kfan bf16 splits overlay the (not-yet-written) H buffer
  bf16*   KH   = (bf16*)(ws + OFF_H);
  bf16*   KM   = KH + KFA_ELT;
  bf16*   KL   = KM + KFA_ELT;

  // weight transpose + bf16 convert
  k_transpose_bf16<<<dim3(NH / 32, DIM / 32), dim3(32, 8), 0, stream>>>(w1, W1T, DIM, NH);
  k_transpose_bf16<<<dim3(NH / 32, NH / 32), dim3(32, 8), 0, stream>>>(w2, W2T, NH, NH);

  // compression setup
  k_row_invnorm<<<NB * TCLIP, 256, 0, stream>>>(x, INV);
  k_kf_colsum<<<NB, 256, 0, stream>>>(x, INV, S);
  k_redundancy<<<dim3(TKF, NB), 256, 0, stream>>>(x, INV, S, RED);
  k_select_kf<<<NB, 256, 0, stream>>>(RED, KSRC, KFC, IDXA);
  k_gather_kf<<<dim3(KKEEP, NB), 256, 0, stream>>>(x, KSRC, KFS);

  // 7 fixed merge iterations: (n_incr, n_to_merge)
  run_iter<588, 196>(x, INV, KFS, KFC, KH, KM, KL, IDXA, IDXB, MAXS, BK, MSRC, MTGT, stream);
  run_iter<392, 130>(x, INV, KFS, KFC, KH, KM, KL, IDXB, IDXA, MAXS, BK, MSRC, MTGT, stream);
  run_iter<262,  87>(x, INV, KFS, KFC, KH, KM, KL, IDXA, IDXB, MAXS, BK, MSRC, MTGT, stream);
  run_iter<175,  58>(x, INV, KFS, KFC, KH, KM, KL, IDXB, IDXA, MAXS, BK, MSRC, MTGT, stream);
  run_iter<117,  39>(x, INV, KFS, KFC, KH, KM, KL, IDXA, IDXB, MAXS, BK, MSRC, MTGT, stream);
  run_iter< 78,  26>(x, INV, KFS, KFC, KH, KM, KL, IDXB, IDXA, MAXS, BK, MSRC, MTGT, stream);
  run_iter< 52,   3>(x, INV, KFS, KFC, KH, KM, KL, IDXA, IDXB, MAXS, BK, MSRC, MTGT, stream);

  k_assemble_z<<<dim3(TKF, NB), 256, 0, stream>>>(x, KFS, KFC, IDXB, Z);

  // MLP: h = gelu(z@w1 + b1) ; out = h@w2 + b2
  k_gemm_bt<0><<<dim3(MR / 128, NH / 128), 256, 0, stream>>>(Z, W1T, b1, nullptr, H, DIM);
  k_gemm_bt<1><<<dim3(MR / 128, NH / 128), 256, 0, stream>>>(H, W2T, b2, out, nullptr, NH);
}

// Round 3
// 2517.100 us; speedup vs baseline: 2.2413x; 1.0292x over previous
//
#include <hip/hip_runtime.h>
#include <math.h>

typedef __bf16 bf16;
typedef __bf16 bf16x8 __attribute__((ext_vector_type(8)));
typedef float f32x4 __attribute__((ext_vector_type(4)));

#define DEV static __device__ __forceinline__

constexpr int NB    = 64;    // clips
constexpr int TCLIP = 784;   // tokens per clip
constexpr int TKF   = 196;   // keyframe tokens
constexpr int KKEEP = 147;   // kept keyframes
constexpr int NINC0 = 588;   // initial incremental tokens
constexpr int DIM   = 1024;
constexpr int MR    = NB * TKF;  // 12544 rows into the MLP
constexpr int NH    = 4096;

// ---- workspace layout (bytes) ----
constexpr size_t OFF_W1T  = 0;
constexpr size_t OFF_W2T  = OFF_W1T  + (size_t)NH*DIM*2;       // w1^T bf16 (4096x1024)
constexpr size_t OFF_Z    = OFF_W2T  + (size_t)NH*NH*2;        // w2^T bf16 (4096x4096)
constexpr size_t OFF_H    = OFF_Z    + (size_t)MR*DIM*2;       // z bf16 (12544x1024)
constexpr size_t OFF_KFS  = OFF_H    + (size_t)MR*NH*2;        // h bf16 (12544x4096)
constexpr size_t OFF_KFC  = OFF_KFS  + (size_t)NB*KKEEP*DIM*4; // kf_sum f32
constexpr size_t OFF_INV  = OFF_KFC  + (size_t)NB*KKEEP*4;     // kf_count f32
constexpr size_t OFF_S    = OFF_INV  + (size_t)NB*TCLIP*8;     // row inv-norms f64
constexpr size_t OFF_RED  = OFF_S    + (size_t)NB*DIM*8;       // kf_n column sums f64
constexpr size_t OFF_KSRC = OFF_RED  + (size_t)NB*TKF*4;       // redundancy f32
constexpr size_t OFF_IDXA = OFF_KSRC + (size_t)NB*KKEEP*4;
constexpr size_t OFF_IDXB = OFF_IDXA + (size_t)NB*NINC0*4;
constexpr size_t OFF_MAXS = OFF_IDXB + (size_t)NB*NINC0*4;
constexpr size_t OFF_BK   = OFF_MAXS + (size_t)NB*NINC0*4;
constexpr size_t OFF_MSRC = OFF_BK   + (size_t)NB*NINC0*4;
constexpr size_t OFF_MTGT = OFF_MSRC + (size_t)NB*TKF*4;
// kfan 3-way bf16 splits live in the H region (GEMM1 output, written only
// after the merge iterations finish): 3 * 64*147*1024*2B = 57.9 MB <= 102.8 MB
constexpr size_t KFA_ELT  = (size_t)NB * KKEEP * DIM;

// ------------------------------------------------------------------
// transpose fp32 (R x C) -> bf16 (C x R)
__global__ void k_transpose_bf16(const float* __restrict__ in, bf16* __restrict__ out,
                                 int R, int C) {
  __shared__ float t[32][33];
  int c0 = blockIdx.x * 32, r0 = blockIdx.y * 32;
  int tx = threadIdx.x, ty = threadIdx.y;
#pragma unroll
  for (int i = 0; i < 4; i++) t[ty + 8*i][tx] = in[(size_t)(r0 + ty + 8*i) * C + c0 + tx];
  __syncthreads();
#pragma unroll
  for (int i = 0; i < 4; i++)
    out[(size_t)(c0 + ty + 8*i) * R + r0 + tx] = (bf16)t[tx][ty + 8*i];
}

// per-row 1/max(||row||,eps), fp64 accumulation, one block per row
__global__ void k_row_invnorm(const float* __restrict__ x, double* __restrict__ invn) {
  __shared__ double sm[256];
  int row = blockIdx.x, tid = threadIdx.x;
  const float* p = x + (size_t)row * DIM;
  double a = 0.0;
  for (int c = tid; c < DIM; c += 256) { double v = p[c]; a += v * v; }
  sm[tid] = a; __syncthreads();
#pragma unroll
  for (int s = 128; s >= 1; s >>= 1) { if (tid < s) sm[tid] += sm[tid + s]; __syncthreads(); }
  if (tid == 0) invn[row] = 1.0 / fmax(sqrt(sm[0]), 1e-12);
}

// S[b][c] = sum_i fp32(x_kf[b][i][c] * invn) ; fp64 accumulate, ascending i
// grid: NB*4 blocks, each block owns 256 columns (1 col/thread)
__global__ void k_kf_colsum(const float* __restrict__ x, const double* __restrict__ invn,
                            double* __restrict__ S) {
  int b = blockIdx.x >> 2, tid = threadIdx.x;
  int c = ((blockIdx.x & 3) << 8) + tid;
  __shared__ double iv[TKF];
  for (int i = tid; i < TKF; i += 256) iv[i] = invn[b * TCLIP + i];
  __syncthreads();
  double s = 0.0;
  for (int i = 0; i < TKF; i++) {
    float kn = (float)((double)x[((size_t)b * TCLIP + i) * DIM + c] * iv[i]);
    s += (double)kn;
  }
  S[b * DIM + c] = s;
}

// redundancy[b][i] = kf_n_i . S - 1
__global__ void k_redundancy(const float* __restrict__ x, const double* __restrict__ invn,
                             const double* __restrict__ S, float* __restrict__ red) {
  __shared__ double sm[256];
  int i = blockIdx.x, b = blockIdx.y, tid = threadIdx.x;
  const float* p = x + ((size_t)b * TCLIP + i) * DIM;
  double iv = invn[b * TCLIP + i];
  double a = 0.0;
  for (int c = tid; c < DIM; c += 256) {
    float kn = (float)((double)p[c] * iv);
    a += (double)kn * S[b * DIM + c];
  }
  sm[tid] = a; __syncthreads();
#pragma unroll
  for (int s = 128; s >= 1; s >>= 1) { if (tid < s) sm[tid] += sm[tid + s]; __syncthreads(); }
  if (tid == 0) red[b * TKF + i] = (float)(sm[0] - 1.0);
}

// keep 147 lowest-redundancy kf (stable ascending argsort), init count & incr index list
__global__ void k_select_kf(const float* __restrict__ red, int* __restrict__ kf_src,
                            float* __restrict__ kfcnt, int* __restrict__ idxA) {
  __shared__ float r[TKF];
  __shared__ int keep[TKF];
  int b = blockIdx.x, tid = threadIdx.x;
  if (tid < TKF) r[tid] = red[b * TKF + tid];
  __syncthreads();
  if (tid < TKF) {
    float ri = r[tid]; int rank = 0;
    for (int j = 0; j < TKF; j++) rank += (r[j] < ri) + ((j < tid) && (r[j] == ri));
    keep[tid] = rank < KKEEP;
  }
  __syncthreads();
  if (tid < TKF && keep[tid]) {
    int pos = 0;
    for (int j = 0; j < tid; j++) pos += keep[j];
    kf_src[b * KKEEP + pos] = tid;
  }
  if (tid < KKEEP) kfcnt[b * KKEEP + tid] = 1.0f;
  for (int u = tid; u < NINC0; u += 256) idxA[b * NINC0 + u] = u;
}

__global__ void k_gather_kf(const float* __restrict__ x, const int* __restrict__ kf_src,
                            float* __restrict__ kfsum) {
  int k = blockIdx.x, b = blockIdx.y, tid = threadIdx.x;
  int sr = kf_src[b * KKEEP + k];
  const float* s = x + ((size_t)b * TCLIP + sr) * DIM;
  float* d = kfsum + ((size_t)b * KKEEP + k) * DIM;
  for (int c = tid; c < DIM; c += 256) d[c] = s[c];
}

// kfan = l2norm(kf_sum / count) in fp32, emitted as 3-way bf16 split (hi+mid+lo)
__global__ void k_kfa(const float* __restrict__ kfsum, const float* __restrict__ kfcnt,
                      bf16* __restrict__ khi, bf16* __restrict__ kmid,
                      bf16* __restrict__ klo) {
  __shared__ double sm[256];
  int k = blockIdx.x, b = blockIdx.y, tid = threadIdx.x;
  float cnt = kfcnt[b * KKEEP + k];
  size_t base = ((size_t)b * KKEEP + k) * DIM;
  const float* s = kfsum + base;
  float av[4]; double a = 0.0;
#pragma unroll
  for (int j = 0; j < 4; j++) { av[j] = s[tid + 256*j] / cnt; a += (double)av[j] * av[j]; }
  sm[tid] = a; __syncthreads();
#pragma unroll
  for (int sdt = 128; sdt >= 1; sdt >>= 1) { if (tid < sdt) sm[tid] += sm[tid + sdt]; __syncthreads(); }
  float nf = fmaxf((float)sqrt(sm[0]), 1e-12f);
#pragma unroll
  for (int j = 0; j < 4; j++) {
    float v = av[j] / nf;
    bf16 h = (bf16)v;
    float r1 = v - (float)h;
    bf16 m = (bf16)r1;
    float r2 = r1 - (float)m;
    khi[base + tid + 256*j]  = h;
    kmid[base + tid + 256*j] = m;
    klo[base + tid + 256*j]  = (bf16)r2;
  }
}

// ---- MFMA emulated-fp32 sim + fused column max/argmax ----
// LDS tile layout is XOR-chunk-swizzled: the 16B chunk of (row, k8) lives at
// column (k8 ^ ((row>>1)&3)) — spreads fragment reads over 8 bank-groups.
template <int NI>
__global__ __launch_bounds__(256) void k_sim_mfma(const float* __restrict__ x,
                                                  const double* __restrict__ invn,
                                                  const bf16* __restrict__ khi,
                                                  const bf16* __restrict__ kmid,
                                                  const bf16* __restrict__ klo,
                                                  const int* __restrict__ idx_cur,
                                                  float* __restrict__ max_sim,
                                                  int* __restrict__ best_kf) {
  __shared__ __align__(16) bf16 Ah[160 * 32];
  __shared__ __align__(16) bf16 Am[160 * 32];
  __shared__ __align__(16) bf16 Al[160 * 32];
  __shared__ __align__(16) bf16 Bh[64 * 32];
  __shared__ __align__(16) bf16 Bm[64 * 32];
  __shared__ __align__(16) bf16 Bl[64 * 32];
  __shared__ int toks[64];
  __shared__ double ivv[64];

  int b = blockIdx.y, p0 = blockIdx.x * 64, tid = threadIdx.x;
  int w = tid >> 6, l = tid & 63;

  if (tid < 64) {
    int p = p0 + tid;
    bool ok = p < NI;
    toks[tid] = ok ? idx_cur[b * NINC0 + p] : 0;
    ivv[tid] = ok ? invn[b * TCLIP + TKF + toks[tid]] : 0.0;
  }

  f32x4 acc[10];
#pragma unroll
  for (int t = 0; t < 10; t++) acc[t] = f32x4{0.f, 0.f, 0.f, 0.f};

  int brow = tid >> 2;                                   // B staging: token row 0..63
  int bk8g = ((tid & 3) ^ ((tid >> 3) & 3)) * 8;         // swizzled global k-chunk
  int bcol = (tid & 3) * 8;                              // LDS chunk column
  size_t kbase = (size_t)b * KKEEP * DIM;

  for (int kk = 0; kk < DIM; kk += 32) {
    __syncthreads();
    // stage kfan splits: 160 rows x 32 k (rows >=147 zero), swizzled chunks
#pragma unroll
    for (int j = 0; j < 3; j++) {
      int c = tid + 256 * j;
      if (c < 640) {
        int row = c >> 2, cc = (c & 3);
        int k8g = (cc ^ ((row >> 1) & 3)) * 8;
        uint4 vh = {0,0,0,0}, vm = {0,0,0,0}, vl = {0,0,0,0};
        if (row < KKEEP) {
          size_t g = kbase + (size_t)row * DIM + kk + k8g;
          vh = *(const uint4*)(khi + g);
          vm = *(const uint4*)(kmid + g);
          vl = *(const uint4*)(klo + g);
        }
        *(uint4*)(Ah + row * 32 + cc * 8) = vh;
        *(uint4*)(Am + row * 32 + cc * 8) = vm;
        *(uint4*)(Al + row * 32 + cc * 8) = vl;
      }
    }
    // stage incr tile: 64 rows x 32 k fp32 -> 3-way split, vector stores
    {
      const float* src = x + ((size_t)b * TCLIP + TKF + toks[brow]) * DIM + kk + bk8g;
      double iv = ivv[brow];
      float4 f0 = *(const float4*)src;
      float4 f1 = *(const float4*)(src + 4);
      float vv[8] = {f0.x, f0.y, f0.z, f0.w, f1.x, f1.y, f1.z, f1.w};
      bf16x8 oh, om, ol;
#pragma unroll
      for (int e = 0; e < 8; e++) {
        float v = (float)((double)vv[e] * iv);
        bf16 h = (bf16)v;
        float r1 = v - (float)h;
        bf16 m = (bf16)r1;
        float r2 = r1 - (float)m;
        oh[e] = h; om[e] = m; ol[e] = (bf16)r2;
      }
      int o = brow * 32 + bcol;
      *(bf16x8*)(Bh + o) = oh; *(bf16x8*)(Bm + o) = om; *(bf16x8*)(Bl + o) = ol;
    }
    __syncthreads();

    int ko_sw = (((l >> 4) ^ ((l >> 1) & 3)) << 3);      // swizzled fragment chunk
    int fo = ((w * 16 + (l & 15)) << 5) + ko_sw;
    bf16x8 fbh = *(const bf16x8*)(Bh + fo);
    bf16x8 fbm = *(const bf16x8*)(Bm + fo);
    bf16x8 fbl = *(const bf16x8*)(Bl + fo);
#pragma unroll
    for (int t = 0; t < 10; t++) {
      int ao = ((t * 16 + (l & 15)) << 5) + ko_sw;
      bf16x8 fah = *(const bf16x8*)(Ah + ao);
      bf16x8 fam = *(const bf16x8*)(Am + ao);
      bf16x8 fal = *(const bf16x8*)(Al + ao);
      acc[t] = __builtin_amdgcn_mfma_f32_16x16x32_bf16(fah, fbh, acc[t], 0, 0, 0);
      acc[t] = __builtin_amdgcn_mfma_f32_16x16x32_bf16(fah, fbm, acc[t], 0, 0, 0);
      acc[t] = __builtin_amdgcn_mfma_f32_16x16x32_bf16(fam, fbh, acc[t], 0, 0, 0);
      acc[t] = __builtin_amdgcn_mfma_f32_16x16x32_bf16(fam, fbm, acc[t], 0, 0, 0);
      acc[t] = __builtin_amdgcn_mfma_f32_16x16x32_bf16(fah, fbl, acc[t], 0, 0, 0);
      acc[t] = __builtin_amdgcn_mfma_f32_16x16x32_bf16(fal, fbh, acc[t], 0, 0, 0);
    }
  }

  // per-lane max over rows (ascending => ties keep lowest kf)
  float vmax = -3.0e38f; int varg = 1 << 30;
  int g4 = (l >> 4) << 2;
#pragma unroll
  for (int t = 0; t < 10; t++) {
#pragma unroll
    for (int r = 0; r < 4; r++) {
      int row = t * 16 + g4 + r;
      float v = acc[t][r];
      if (row < KKEEP && v > vmax) { vmax = v; varg = row; }
    }
  }
#pragma unroll
  for (int off = 16; off <= 32; off <<= 1) {
    float ov = __shfl_xor(vmax, off, 64);
    int   oa = __shfl_xor(varg, off, 64);
    if (ov > vmax || (ov == vmax && oa < varg)) { vmax = ov; varg = oa; }
  }
  if (l < 16) {
    int p = p0 + w * 16 + l;
    if (p < NI) { max_sim[b * NINC0 + p] = vmax; best_kf[b * NINC0 + p] = varg; }
  }
}

// stable descending rank of max_sim; emit merge list (rank order) + compacted keep list
template <int NI, int NM>
__global__ void k_rank_merge(const float* __restrict__ max_sim, const int* __restrict__ best_kf,
                             const int* __restrict__ idx_cur, int* __restrict__ idx_next,
                             int* __restrict__ msrc, int* __restrict__ mtgt) {
  __shared__ float s[NINC0];
  __shared__ short dr[NINC0];
  int b = blockIdx.x, tid = threadIdx.x;
  for (int i = tid; i < NI; i += 256) s[i] = max_sim[b * NINC0 + i];
  __syncthreads();
  for (int i = tid; i < NI; i += 256) {
    float si = s[i]; int cnt = 0;
    for (int j = 0; j < NI; j++) cnt += (s[j] > si) + ((j < i) && (s[j] == si));
    dr[i] = (short)cnt;
  }
  __syncthreads();
  for (int i = tid; i < NI; i += 256) {
    int r = dr[i];
    if (r < NM) {
      mtgt[b * TKF + r] = best_kf[b * NINC0 + i];
      msrc[b * TKF + r] = idx_cur[b * NINC0 + i];
    } else {
      int pos = 0;
      for (int j = 0; j < i; j++) pos += (dr[j] >= NM);
      idx_next[b * NINC0 + pos] = idx_cur[b * NINC0 + i];
    }
  }
}

// sequential (rank-order) scatter-add into kf_sum — matches np.add.at semantics
template <int NM>
__global__ void k_merge(const float* __restrict__ x, const int* __restrict__ msrc,
                        const int* __restrict__ mtgt, float* __restrict__ kfsum,
                        float* __restrict__ kfcnt) {
  int k = blockIdx.x, b = blockIdx.y, tid = threadIdx.x;
  float* drow = kfsum + ((size_t)b * KKEEP + k) * DIM;
  float acc[4];
#pragma unroll
  for (int j = 0; j < 4; j++) acc[j] = drow[tid + 256*j];
  int adds = 0;
  for (int m = 0; m < NM; m++) {
    int tgt = mtgt[b * TKF + m];
    if (tgt == k) {
      int u = msrc[b * TKF + m];
      const float* r = x + ((size_t)b * TCLIP + TKF + u) * DIM;
#pragma unroll
      for (int j = 0; j < 4; j++) acc[j] += r[tid + 256*j];
      adds++;
    }
  }
#pragma unroll
  for (int j = 0; j < 4; j++) drow[tid + 256*j] = acc[j];
  if (tid == 0 && adds) kfcnt[b * KKEEP + k] += (float)adds;
}

// z = concat(kf_sum/count, kept incr) -> bf16
__global__ void k_assemble_z(const float* __restrict__ x, const float* __restrict__ kfsum,
                             const float* __restrict__ kfcnt, const int* __restrict__ idx_fin,
                             bf16* __restrict__ z) {
  int r = blockIdx.x, b = blockIdx.y, tid = threadIdx.x;
  bf16* zr = z + ((size_t)b * TKF + r) * DIM;
  if (r < KKEEP) {
    float cnt = kfcnt[b * KKEEP + r];
    const float* s = kfsum + ((size_t)b * KKEEP + r) * DIM;
    for (int c = tid; c < DIM; c += 256) zr[c] = (bf16)(s[c] / cnt);
  } else {
    int u = idx_fin[b * NINC0 + (r - KKEEP)];
    const float* s = x + ((size_t)b * TCLIP + TKF + u) * DIM;
    for (int c = tid; c < DIM; c += 256) zr[c] = (bf16)s[c];
  }
}

// ---- bf16 GEMM: C = A(MxK) * Bt(NxK)^T, 128x128 tile, BK=32 ----
// XOR-chunk-swizzled LDS (conflict-free fragment reads) + grouped tile remap
// (GROUP_M=8 m-blocks share B across all n-blocks -> A fetched ~once).
DEV void gl2lds16(const bf16* g, bf16* l) {
  __builtin_amdgcn_global_load_lds((const __attribute__((address_space(1))) void*)g,
                                   (__attribute__((address_space(3))) void*)l, 16, 0, 0);
}

constexpr int GRM = MR / 128;   // 98 m-blocks
constexpr int GRN = NH / 128;   // 32 n-blocks
constexpr int GRP = 8;          // m-group for L2 reuse

template <int EPI>  // 0: +bias, exact gelu, store bf16 ; 1: +bias, store fp32
__global__ __launch_bounds__(256) void k_gemm_bt(const bf16* __restrict__ A,
                                                 const bf16* __restrict__ Bt,
                                                 const float* __restrict__ bias,
                                                 float* __restrict__ outF,
                                                 bf16* __restrict__ outB, int K) {
  __shared__ __align__(16) bf16 As[128 * 32];
  __shared__ __align__(16) bf16 Bs[128 * 32];
  int tid = threadIdx.x, w = tid >> 6, l = tid & 63;

  // grouped remap (triton-style)
  int bid = blockIdx.x;
  int nig = GRP * GRN;
  int gid = bid / nig;
  int fm = gid * GRP;
  int gsz = min(GRP, GRM - fm);
  int idx = bid % nig;
  int m0 = (fm + idx % gsz) * 128;
  int n0 = (idx / gsz) * 128;

  int wr = w >> 1, wc = w & 1;
  f32x4 acc[4][4];
#pragma unroll
  for (int i = 0; i < 4; i++)
#pragma unroll
    for (int j = 0; j < 4; j++) acc[i][j] = f32x4{0.f, 0.f, 0.f, 0.f};

  int srow = w * 32 + (l >> 2);
  int scol = ((l & 3) ^ ((l >> 3) & 3)) * 8;   // swizzled global k-chunk
  const bf16* gA = A + (size_t)(m0 + srow) * K + scol;
  const bf16* gB = Bt + (size_t)(n0 + srow) * K + scol;
  const size_t str16 = (size_t)16 * K;
  bf16* lA0 = As + (w * 32) * 32;
  bf16* lA1 = As + (w * 32 + 16) * 32;
  bf16* lB0 = Bs + (w * 32) * 32;
  bf16* lB1 = Bs + (w * 32 + 16) * 32;

  int fro = (l & 15);
  int ko_sw = (((l >> 4) ^ ((l >> 1) & 3)) << 3);  // swizzled fragment chunk
  for (int kk = 0; kk < K; kk += 32) {
    __syncthreads();
    gl2lds16(gA + kk, lA0);
    gl2lds16(gA + kk + str16, lA1);
    gl2lds16(gB + kk, lB0);
    gl2lds16(gB + kk + str16, lB1);
    __syncthreads();
    bf16x8 af[4], bfr[4];
#pragma unroll
    for (int mi = 0; mi < 4; mi++)
      af[mi] = *(const bf16x8*)(As + (wr * 64 + mi * 16 + fro) * 32 + ko_sw);
#pragma unroll
    for (int ni = 0; ni < 4; ni++)
      bfr[ni] = *(const bf16x8*)(Bs + (wc * 64 + ni * 16 + fro) * 32 + ko_sw);
#pragma unroll
    for (int mi = 0; mi < 4; mi++)
#pragma unroll
      for (int ni = 0; ni < 4; ni++)
        acc[mi][ni] = __builtin_amdgcn_mfma_f32_16x16x32_bf16(af[mi], bfr[ni], acc[mi][ni], 0, 0, 0);
  }
  int col0 = n0 + wc * 64 + (l & 15);
  int row0 = m0 + wr * 64 + ((l >> 4) << 2);
#pragma unroll
  for (int ni = 0; ni < 4; ni++) {
    int col = col0 + ni * 16;
    float bv = bias[col];
#pragma unroll
    for (int mi = 0; mi < 4; mi++) {
#pragma unroll
      for (int r = 0; r < 4; r++) {
        int row = row0 + mi * 16 + r;
        float v = acc[mi][ni][r] + bv;
        if (EPI == 0) {
          float g = 0.5f * v * (1.0f + erff(v * 0.70710678118654752f));
          outB[(size_t)row * NH + col] = (bf16)g;
        } else {
          outF[(size_t)row * NH + col] = v;
        }
      }
    }
  }
}

// ------------------------------------------------------------------
template <int NI, int NM>
static void run_iter(const float* x, const double* INV, float* KFS, float* KFC,
                     bf16* KH, bf16* KM, bf16* KL,
                     const int* cur, int* next, float* MAXS, int* BK, int* MSRC, int* MTGT,
                     hipStream_t stream) {
  k_kfa<<<dim3(KKEEP, NB), 256, 0, stream>>>(KFS, KFC, KH, KM, KL);
  k_sim_mfma<NI><<<dim3((NI + 63) / 64, NB), 256, 0, stream>>>(x, INV, KH, KM, KL, cur, MAXS, BK);
  k_rank_merge<NI, NM><<<NB, 256, 0, stream>>>(MAXS, BK, cur, next, MSRC, MTGT);
  k_merge<NM><<<dim3(KKEEP, NB), 256, 0, stream>>>(x, MSRC, MTGT, KFS, KFC);
}

extern "C" void kernel_launch(void* const* d_in, const int* in_sizes, int n_in,
                              void* d_out, int out_size, void* d_ws, size_t ws_size,
                              hipStream_t stream) {
  const float* x  = (const float*)d_in[0];
  const float* w1 = (const float*)d_in[1];
  const float* b1 = (const float*)d_in[2];
  const float* w2 = (const float*)d_in[3];
  const float* b2 = (const float*)d_in[4];
  float* out = (float*)d_out;
  char* ws = (char*)d_ws;

  bf16*   W1T  = (bf16*)(ws + OFF_W1T);
  bf16*   W2T  = (bf16*)(ws + OFF_W2T);
  bf16*   Z    = (bf16*)(ws + OFF_Z);
  bf16*   H    = (bf16*)(ws + OFF_H);
  float*  KFS  = (float*)(ws + OFF_KFS);
  float*  KFC  = (float*)(ws + OFF_KFC);
  double* INV  = (double*)(ws + OFF_INV);
  double* S    = (double*)(ws + OFF_S);
  float*  RED  = (float*)(ws + OFF_RED);
  int*    KSRC = (int*)(ws + OFF_KSRC);
  int*    IDXA = (int*)(ws + OFF_IDXA);
  int*    IDXB = (int*)(ws + OFF_IDXB);
  float*  MAXS = (float*)(ws + OFF_MAXS);
  int*    BK   = (int*)(ws + OFF_BK);
  int*    MSRC = (int*)(ws + OFF_MSRC);
  int*    MTGT = (int*)(ws + OFF_MTGT);
  // kfan bf16 splits overlay the (not-yet-written) H buffer
  bf16*   KH   = (bf16*)(ws + OFF_H);
  bf16*   KM   = KH + KFA_ELT;
  bf16*   KL   = KM + KFA_ELT;

  // weight transpose + bf16 convert
  k_transpose_bf16<<<dim3(NH / 32, DIM / 32), dim3(32, 8), 0, stream>>>(w1, W1T, DIM, NH);
  k_transpose_bf16<<<dim3(NH / 32, NH / 32), dim3(32, 8), 0, stream>>>(w2, W2T, NH, NH);

  // compression setup
  k_row_invnorm<<<NB * TCLIP, 256, 0, stream>>>(x, INV);
  k_kf_colsum<<<NB * 4, 256, 0, stream>>>(x, INV, S);
  k_redundancy<<<dim3(TKF, NB), 256, 0, stream>>>(x, INV, S, RED);
  k_select_kf<<<NB, 256, 0, stream>>>(RED, KSRC, KFC, IDXA);
  k_gather_kf<<<dim3(KKEEP, NB), 256, 0, stream>>>(x, KSRC, KFS);

  // 7 fixed merge iterations: (n_incr, n_to_merge)
  run_iter<588, 196>(x, INV, KFS, KFC, KH, KM, KL, IDXA, IDXB, MAXS, BK, MSRC, MTGT, stream);
  run_iter<392, 130>(x, INV, KFS, KFC, KH, KM, KL, IDXB, IDXA, MAXS, BK, MSRC, MTGT, stream);
  run_iter<262,  87>(x, INV, KFS, KFC, KH, KM, KL, IDXA, IDXB, MAXS, BK, MSRC, MTGT, stream);
  run_iter<175,  58>(x, INV, KFS, KFC, KH, KM, KL, IDXB, IDXA, MAXS, BK, MSRC, MTGT, stream);
  run_iter<117,  39>(x, INV, KFS, KFC, KH, KM, KL, IDXA, IDXB, MAXS, BK, MSRC, MTGT, stream);
  run_iter< 78,  26>(x, INV, KFS, KFC, KH, KM, KL, IDXB, IDXA, MAXS, BK, MSRC, MTGT, stream);
  run_iter< 52,   3>(x, INV, KFS, KFC, KH, KM, KL, IDXA, IDXB, MAXS, BK, MSRC, MTGT, stream);

  k_assemble_z<<<dim3(TKF, NB), 256, 0, stream>>>(x, KFS, KFC, IDXB, Z);

  // MLP: h = gelu(z@w1 + b1) ; out = h@w2 + b2
  k_gemm_bt<0><<<GRM * GRN, 256, 0, stream>>>(Z, W1T, b1, nullptr, H, DIM);
  k_gemm_bt<1><<<GRM * GRN, 256, 0, stream>>>(H, W2T, b2, out, nullptr, NH);
}